// Round 1
// baseline (157.398 us; speedup 1.0000x reference)
//
#include <hip/hip_runtime.h>

// DAG MLP: L=8 layers, D=64, B=262144, 28 all-to-all forward connections.
// outs[j] += relu(outs[i] @ W_c^T + b_c) for all i<j; output = outs[7].
// Fully fused: each wave owns 16 batch rows; activations live as bf16 MFMA
// A-fragments in registers; weights stream through LDS (bf16, XOR-swizzled).

#define DD 64
#define NCONN 28
#define THREADS 512            // 8 waves
#define ROWS_PER_BLOCK 128     // 8 waves * 16 rows

typedef __bf16 bf16x8 __attribute__((ext_vector_type(8)));
typedef float f32x4 __attribute__((ext_vector_type(4)));
typedef unsigned short u16x8 __attribute__((ext_vector_type(8)));

__device__ __forceinline__ unsigned short f2bfu(float f) {
    return __builtin_bit_cast(unsigned short, (__bf16)f);
}

// fp32 -> bf16 pre-conversion of the 28 weight matrices into d_ws.
__global__ void wconv_kernel(const float* __restrict__ w,
                             unsigned short* __restrict__ o, int n4) {
    int i = blockIdx.x * blockDim.x + threadIdx.x;
    if (i < n4) {
        float4 v = reinterpret_cast<const float4*>(w)[i];
        ushort4 r;
        r.x = f2bfu(v.x); r.y = f2bfu(v.y); r.z = f2bfu(v.z); r.w = f2bfu(v.w);
        reinterpret_cast<ushort4*>(o)[i] = r;
    }
}

template <bool WSBF16>
__global__ __launch_bounds__(THREADS)
void dag_kernel(const float* __restrict__ x,
                const float* __restrict__ Wf,
                const unsigned short* __restrict__ Wbf,
                const float* __restrict__ bs,
                float* __restrict__ out) {
    // Swizzled bf16 W tile (64x64) shared by all waves; per-wave transpose bounce.
    __shared__ __align__(16) unsigned short sW[DD * DD];         // 8 KB
    __shared__ __align__(16) unsigned short sB[8 * 16 * DD];     // 16 KB

    const int tid  = threadIdx.x;
    const int lane = tid & 63;
    const int wv   = tid >> 6;
    const int l15  = lane & 15;   // A: row / B,D: col
    const int kg   = lane >> 4;   // k-group (A/B), row-group (D)

    // connection c for (src i -> dst j): c = OFFS[i] + (j-i-1)
    constexpr int OFFS[7] = {0, 7, 13, 18, 22, 25, 27};

    const long rowbase = (long)blockIdx.x * ROWS_PER_BLOCK + wv * 16;

    // A-fragments for source layers 0..6, 2 K-steps each (K=64 = 2*32).
    bf16x8 afrag[7][2];

    // Layer 0 = input x: coalesced fp32 loads (each row-group reads 128B runs).
    {
        const float* xr = x + (rowbase + l15) * DD;
#pragma unroll
        for (int s = 0; s < 2; ++s) {
            float4 v0 = *reinterpret_cast<const float4*>(xr + s * 32 + kg * 8);
            float4 v1 = *reinterpret_cast<const float4*>(xr + s * 32 + kg * 8 + 4);
            bf16x8 f;
            f[0] = (__bf16)v0.x; f[1] = (__bf16)v0.y; f[2] = (__bf16)v0.z; f[3] = (__bf16)v0.w;
            f[4] = (__bf16)v1.x; f[5] = (__bf16)v1.y; f[6] = (__bf16)v1.z; f[7] = (__bf16)v1.w;
            afrag[0][s] = f;
        }
    }

    unsigned short* myB = &sB[wv * (16 * DD)];

#pragma unroll
    for (int j = 1; j < 8; ++j) {
        f32x4 acc[4];
#pragma unroll
        for (int t = 0; t < 4; ++t) {
            acc[t][0] = 0.f; acc[t][1] = 0.f; acc[t][2] = 0.f; acc[t][3] = 0.f;
        }

#pragma unroll
        for (int i = 0; i < j; ++i) {
            const int c = OFFS[i] + (j - i - 1);

            __syncthreads();  // previous W fully consumed
            {
                // Stage W[c] (row-major [out=n][in=k]) into LDS, bf16, swizzled:
                // elem(n,k) at n*64 + (k ^ ((n&7)<<3)) — 16B-block permutation.
                const int r   = tid >> 3;
                const int c0  = (tid & 7) << 3;
                const int dst = r * DD + (c0 ^ ((r & 7) << 3));
                if constexpr (WSBF16) {
                    u16x8 v = *reinterpret_cast<const u16x8*>(Wbf + c * (DD * DD) + tid * 8);
                    *reinterpret_cast<u16x8*>(&sW[dst]) = v;
                } else {
                    const float* wp = Wf + c * (DD * DD) + tid * 8;
                    float4 v0 = *reinterpret_cast<const float4*>(wp);
                    float4 v1 = *reinterpret_cast<const float4*>(wp + 4);
                    u16x8 v;
                    v[0] = f2bfu(v0.x); v[1] = f2bfu(v0.y); v[2] = f2bfu(v0.z); v[3] = f2bfu(v0.w);
                    v[4] = f2bfu(v1.x); v[5] = f2bfu(v1.y); v[6] = f2bfu(v1.z); v[7] = f2bfu(v1.w);
                    *reinterpret_cast<u16x8*>(&sW[dst]) = v;
                }
            }
            __syncthreads();  // W[c] ready

#pragma unroll
            for (int t = 0; t < 4; ++t) {
                const int n  = t * 16 + l15;           // output column
                const float bv = bs[c * DD + n];       // bias per column
                f32x4 C = {bv, bv, bv, bv};
                // B-operand frag: lane holds W[n][ks*32 + kg*8 .. +7]
                u16x8 rw0 = *reinterpret_cast<const u16x8*>(
                    &sW[n * DD + ((kg * 8) ^ ((n & 7) << 3))]);
                u16x8 rw1 = *reinterpret_cast<const u16x8*>(
                    &sW[n * DD + ((32 + kg * 8) ^ ((n & 7) << 3))]);
                C = __builtin_amdgcn_mfma_f32_16x16x32_bf16(
                        afrag[i][0], __builtin_bit_cast(bf16x8, rw0), C, 0, 0, 0);
                C = __builtin_amdgcn_mfma_f32_16x16x32_bf16(
                        afrag[i][1], __builtin_bit_cast(bf16x8, rw1), C, 0, 0, 0);
                acc[t][0] += fmaxf(C[0], 0.f);
                acc[t][1] += fmaxf(C[1], 0.f);
                acc[t][2] += fmaxf(C[2], 0.f);
                acc[t][3] += fmaxf(C[3], 0.f);
            }
        }

        if (j < 7) {
            // D-layout (lane: col=l15, rows kg*4+q) -> A-frag layout via
            // per-wave LDS bounce (same swizzle as W). Wave-private: no barrier.
#pragma unroll
            for (int t = 0; t < 4; ++t) {
                const int n = t * 16 + l15;
#pragma unroll
                for (int q = 0; q < 4; ++q) {
                    const int m = kg * 4 + q;
                    myB[m * DD + (n ^ ((m & 7) << 3))] = f2bfu(acc[t][q]);
                }
            }
            asm volatile("s_waitcnt lgkmcnt(0)" ::: "memory");
#pragma unroll
            for (int s = 0; s < 2; ++s) {
                u16x8 ra = *reinterpret_cast<const u16x8*>(
                    &myB[l15 * DD + ((s * 32 + kg * 8) ^ ((l15 & 7) << 3))]);
                afrag[j][s] = __builtin_bit_cast(bf16x8, ra);
            }
        } else {
            // Final layer: write fp32, 64B-contiguous runs per 16-lane group.
            float* orow = out + rowbase * DD;
#pragma unroll
            for (int t = 0; t < 4; ++t) {
#pragma unroll
                for (int q = 0; q < 4; ++q) {
                    const int m = kg * 4 + q;
                    orow[m * DD + t * 16 + l15] = acc[t][q];
                }
            }
        }
    }
}

extern "C" void kernel_launch(void* const* d_in, const int* in_sizes, int n_in,
                              void* d_out, int out_size, void* d_ws, size_t ws_size,
                              hipStream_t stream) {
    const float* x  = (const float*)d_in[0];
    const float* Ws = (const float*)d_in[1];
    const float* bs = (const float*)d_in[2];
    float* out = (float*)d_out;

    const int nrows = in_sizes[0] / DD;           // 262144
    const int grid  = nrows / ROWS_PER_BLOCK;     // 2048

    const size_t wbf_bytes = (size_t)NCONN * DD * DD * sizeof(unsigned short);
    if (ws_size >= wbf_bytes) {
        unsigned short* wbf = (unsigned short*)d_ws;
        const int n4 = NCONN * DD * DD / 4;       // 28672
        wconv_kernel<<<(n4 + 255) / 256, 256, 0, stream>>>(Ws, wbf, n4);
        dag_kernel<true><<<grid, THREADS, 0, stream>>>(x, Ws, wbf, bs, out);
    } else {
        dag_kernel<false><<<grid, THREADS, 0, stream>>>(x, Ws, nullptr, bs, out);
    }
}